// Round 2
// baseline (330.584 us; speedup 1.0000x reference)
//
#include <hip/hip_runtime.h>
#include <hip/hip_bf16.h>

#define NH 128
#define NW 128
#define ND 128
#define HWD (NH * NW * ND)
#define NB 2

// ---------- dtype-generic load/store (compute is always fp32) ----------
template <typename T>
__device__ __forceinline__ float ldT(const T* p, int idx);
template <>
__device__ __forceinline__ float ldT<float>(const float* p, int idx) { return p[idx]; }
template <>
__device__ __forceinline__ float ldT<__hip_bfloat16>(const __hip_bfloat16* p, int idx) {
    return __bfloat162float(p[idx]);
}

template <typename T>
__device__ __forceinline__ void stT(T* p, int idx, float v);
template <>
__device__ __forceinline__ void stT<float>(float* p, int idx, float v) { p[idx] = v; }
template <>
__device__ __forceinline__ void stT<__hip_bfloat16>(__hip_bfloat16* p, int idx, float v) {
    p[idx] = __float2bfloat16(v);
}

// ---------- dtype probe: even-index bf16 reinterpretation of f32 data is wild ----------
__global__ void detect_dtype(const void* ddf_raw, int* flag) {
    __shared__ int cnt;
    if (threadIdx.x == 0) cnt = 0;
    __syncthreads();
    const __hip_bfloat16* p = (const __hip_bfloat16*)ddf_raw;
    // even indices only; interior of ddf; in-bounds for both interpretations
    float v = __bfloat162float(p[131072 + 2 * threadIdx.x]);
    if (!(fabsf(v) <= 1e4f))   // catches NaN too
        atomicAdd(&cnt, 1);
    __syncthreads();
    if (threadIdx.x == 0) *flag = (cnt > 16) ? 1 : 0;
}

// ---------- per-voxel work ----------
template <typename T>
__device__ __forceinline__ void voxel(const T* __restrict__ dti,
                                      const T* __restrict__ ddf,
                                      T* __restrict__ out, int tid) {
    const int d = tid & (ND - 1);
    const int w = (tid >> 7) & (NW - 1);
    const int h = (tid >> 14) & (NH - 1);
    const int b = tid >> 21;
    const int sp = tid & (HWD - 1);

    const T* dbase = ddf + b * 3 * HWD;

    float u[3];
#pragma unroll
    for (int c = 0; c < 3; ++c) u[c] = ldT<T>(dbase, c * HWD + sp);

    // Jacobian A = I + grad(ddf), jnp.gradient semantics
    float A[3][3];
#pragma unroll
    for (int c = 0; c < 3; ++c) {
        const T* p = dbase + c * HWD;
        float gh, gw, gd;
        if (h == 0)           gh = ldT<T>(p, sp + NW * ND) - u[c];
        else if (h == NH - 1) gh = u[c] - ldT<T>(p, sp - NW * ND);
        else                  gh = 0.5f * (ldT<T>(p, sp + NW * ND) - ldT<T>(p, sp - NW * ND));
        if (w == 0)           gw = ldT<T>(p, sp + ND) - u[c];
        else if (w == NW - 1) gw = u[c] - ldT<T>(p, sp - ND);
        else                  gw = 0.5f * (ldT<T>(p, sp + ND) - ldT<T>(p, sp - ND));
        if (d == 0)           gd = ldT<T>(p, sp + 1) - u[c];
        else if (d == ND - 1) gd = u[c] - ldT<T>(p, sp - 1);
        else                  gd = 0.5f * (ldT<T>(p, sp + 1) - ldT<T>(p, sp - 1));
        A[c][0] = gh; A[c][1] = gw; A[c][2] = gd;
    }
    A[0][0] += 1.0f; A[1][1] += 1.0f; A[2][2] += 1.0f;

    // Newton polar: U <- 0.5*(zeta*U + inv((zeta*U)^T))
    float U[3][3];
#pragma unroll
    for (int i = 0; i < 3; ++i)
#pragma unroll
        for (int j = 0; j < 3; ++j) U[i][j] = A[i][j];

#pragma unroll
    for (int it = 0; it < 6; ++it) {
        float c00 = U[1][1]*U[2][2] - U[1][2]*U[2][1];
        float c01 = U[0][2]*U[2][1] - U[0][1]*U[2][2];
        float c02 = U[0][1]*U[1][2] - U[0][2]*U[1][1];
        float c10 = U[1][2]*U[2][0] - U[1][0]*U[2][2];
        float c11 = U[0][0]*U[2][2] - U[0][2]*U[2][0];
        float c12 = U[0][2]*U[1][0] - U[0][0]*U[1][2];
        float c20 = U[1][0]*U[2][1] - U[1][1]*U[2][0];
        float c21 = U[0][1]*U[2][0] - U[0][0]*U[2][1];
        float c22 = U[0][0]*U[1][1] - U[0][1]*U[1][0];
        float det = U[0][0]*c00 + U[0][1]*c10 + U[0][2]*c20;
        float zeta = 1.0f / cbrtf(fabsf(det));
        float s = 1.0f / (zeta * det);   // sign of det propagates
        float n00 = 0.5f * (zeta*U[0][0] + c00*s);
        float n01 = 0.5f * (zeta*U[0][1] + c10*s);
        float n02 = 0.5f * (zeta*U[0][2] + c20*s);
        float n10 = 0.5f * (zeta*U[1][0] + c01*s);
        float n11 = 0.5f * (zeta*U[1][1] + c11*s);
        float n12 = 0.5f * (zeta*U[1][2] + c21*s);
        float n20 = 0.5f * (zeta*U[2][0] + c02*s);
        float n21 = 0.5f * (zeta*U[2][1] + c12*s);
        float n22 = 0.5f * (zeta*U[2][2] + c22*s);
        U[0][0]=n00; U[0][1]=n01; U[0][2]=n02;
        U[1][0]=n10; U[1][1]=n11; U[1][2]=n12;
        U[2][0]=n20; U[2][1]=n21; U[2][2]=n22;
    }

    // trilinear warp of 6 channels
    float cx = (float)h + u[0];
    float cy = (float)w + u[1];
    float cz = (float)d + u[2];
    float flx = floorf(cx), fly = floorf(cy), flz = floorf(cz);
    float fx = cx - flx, fy = cy - fly, fz = cz - flz;
    int x0 = (int)flx, y0 = (int)fly, z0 = (int)flz;
    int xi[2], yi[2], zi[2];
    xi[0] = min(max(x0,     0), NH - 1); xi[1] = min(max(x0 + 1, 0), NH - 1);
    yi[0] = min(max(y0,     0), NW - 1); yi[1] = min(max(y0 + 1, 0), NW - 1);
    zi[0] = min(max(z0,     0), ND - 1); zi[1] = min(max(z0 + 1, 0), ND - 1);
    float wx[2] = {1.0f - fx, fx};
    float wy[2] = {1.0f - fy, fy};
    float wz[2] = {1.0f - fz, fz};

    const T* img = dti + b * 6 * HWD;
    float acc[6] = {0.f, 0.f, 0.f, 0.f, 0.f, 0.f};
#pragma unroll
    for (int i = 0; i < 2; ++i) {
#pragma unroll
        for (int j = 0; j < 2; ++j) {
            int rowoff = (xi[i] * NW + yi[j]) * ND;
            float wij = wx[i] * wy[j];
#pragma unroll
            for (int k = 0; k < 2; ++k) {
                float wgt = wij * wz[k];
                int lin = rowoff + zi[k];
#pragma unroll
                for (int ch = 0; ch < 6; ++ch)
                    acc[ch] += wgt * ldT<T>(img, ch * HWD + lin);
            }
        }
    }

    float Dm[3][3];
    Dm[0][0] = acc[0]; Dm[0][1] = acc[1]; Dm[0][2] = acc[3];
    Dm[1][0] = acc[1]; Dm[1][1] = acc[2]; Dm[1][2] = acc[4];
    Dm[2][0] = acc[3]; Dm[2][1] = acc[4]; Dm[2][2] = acc[5];

    float M[3][3];
#pragma unroll
    for (int i = 0; i < 3; ++i)
#pragma unroll
        for (int k = 0; k < 3; ++k)
            M[i][k] = U[0][i]*Dm[0][k] + U[1][i]*Dm[1][k] + U[2][i]*Dm[2][k];

    float T00 = M[0][0]*U[0][0] + M[0][1]*U[1][0] + M[0][2]*U[2][0];
    float T10 = M[1][0]*U[0][0] + M[1][1]*U[1][0] + M[1][2]*U[2][0];
    float T11 = M[1][0]*U[0][1] + M[1][1]*U[1][1] + M[1][2]*U[2][1];
    float T20 = M[2][0]*U[0][0] + M[2][1]*U[1][0] + M[2][2]*U[2][0];
    float T21 = M[2][0]*U[0][1] + M[2][1]*U[1][1] + M[2][2]*U[2][1];
    float T22 = M[2][0]*U[0][2] + M[2][1]*U[1][2] + M[2][2]*U[2][2];

    T* obase = out + b * 6 * HWD + sp;
    stT<T>(obase, 0,       T00);
    stT<T>(obase, HWD,     T10);
    stT<T>(obase, 2 * HWD, T11);
    stT<T>(obase, 3 * HWD, T20);
    stT<T>(obase, 4 * HWD, T21);
    stT<T>(obase, 5 * HWD, T22);
}

__global__ __launch_bounds__(256) void warp_dti_kernel(
    const void* __restrict__ dti,
    const void* __restrict__ ddf,
    void* __restrict__ out,
    const int* __restrict__ flag)
{
    const int tid = blockIdx.x * 256 + threadIdx.x;
    if (*flag) {
        voxel<float>((const float*)dti, (const float*)ddf, (float*)out, tid);
    } else {
        voxel<__hip_bfloat16>((const __hip_bfloat16*)dti, (const __hip_bfloat16*)ddf,
                              (__hip_bfloat16*)out, tid);
    }
}

extern "C" void kernel_launch(void* const* d_in, const int* in_sizes, int n_in,
                              void* d_out, int out_size, void* d_ws, size_t ws_size,
                              hipStream_t stream) {
    int* flag = (int*)d_ws;
    detect_dtype<<<1, 256, 0, stream>>>(d_in[1], flag);
    const int n = NB * HWD;   // 4,194,304 voxels
    warp_dti_kernel<<<n / 256, 256, 0, stream>>>(d_in[0], d_in[1], d_out, flag);
}

// Round 4
// 307.819 us; speedup vs baseline: 1.0740x; 1.0740x over previous
//
#include <hip/hip_runtime.h>

#define NH 128
#define NW 128
#define ND 128
#define HWD (NH * NW * ND)
#define NB 2

__global__ __launch_bounds__(256) void warp_dti_kernel(
    const float* __restrict__ dti,
    const float* __restrict__ ddf,
    float* __restrict__ out)
{
    const int tid = blockIdx.x * 256 + threadIdx.x;   // grid == NB*HWD exactly
    const int d = tid & (ND - 1);
    const int w = (tid >> 7) & (NW - 1);
    const int h = (tid >> 14) & (NH - 1);
    const int b = tid >> 21;
    const int sp = tid & (HWD - 1);                   // h*W*D + w*D + d

    const float* dbase = ddf + b * 3 * HWD;

    // ---- center displacement ----
    float u[3];
#pragma unroll
    for (int c = 0; c < 3; ++c) u[c] = dbase[c * HWD + sp];

    // ---- Jacobian A = I + grad(ddf), jnp.gradient semantics ----
    float A[3][3];
#pragma unroll
    for (int c = 0; c < 3; ++c) {
        const float* p = dbase + c * HWD;
        float gh, gw, gd;
        if (h == 0)           gh = p[sp + NW * ND] - u[c];
        else if (h == NH - 1) gh = u[c] - p[sp - NW * ND];
        else                  gh = 0.5f * (p[sp + NW * ND] - p[sp - NW * ND]);
        if (w == 0)           gw = p[sp + ND] - u[c];
        else if (w == NW - 1) gw = u[c] - p[sp - ND];
        else                  gw = 0.5f * (p[sp + ND] - p[sp - ND]);
        if (d == 0)           gd = p[sp + 1] - u[c];
        else if (d == ND - 1) gd = u[c] - p[sp - 1];
        else                  gd = 0.5f * (p[sp + 1] - p[sp - 1]);
        A[c][0] = gh; A[c][1] = gw; A[c][2] = gd;
    }
    A[0][0] += 1.0f; A[1][1] += 1.0f; A[2][2] += 1.0f;

    // ---- Newton polar: U <- 0.5*(zeta*U + inv((zeta*U)^T)) ----
    // zeta = |det|^{-1/3};  inv((zU)^T)[i][j] = cof(U)[j][i] / (zeta*det)
    // 1/(zeta*det) = sign(det)*|det|^{-2/3} = copysign(zeta^2, det)  -> no divides
    float U[3][3];
#pragma unroll
    for (int i = 0; i < 3; ++i)
#pragma unroll
        for (int j = 0; j < 3; ++j) U[i][j] = A[i][j];

#pragma unroll
    for (int it = 0; it < 6; ++it) {
        float c00 = U[1][1]*U[2][2] - U[1][2]*U[2][1];
        float c01 = U[0][2]*U[2][1] - U[0][1]*U[2][2];
        float c02 = U[0][1]*U[1][2] - U[0][2]*U[1][1];
        float c10 = U[1][2]*U[2][0] - U[1][0]*U[2][2];
        float c11 = U[0][0]*U[2][2] - U[0][2]*U[2][0];
        float c12 = U[0][2]*U[1][0] - U[0][0]*U[1][2];
        float c20 = U[1][0]*U[2][1] - U[1][1]*U[2][0];
        float c21 = U[0][1]*U[2][0] - U[0][0]*U[2][1];
        float c22 = U[0][0]*U[1][1] - U[0][1]*U[1][0];
        float det = U[0][0]*c00 + U[0][1]*c10 + U[0][2]*c20;

        float l    = __log2f(fabsf(det));                       // v_log_f32
        float zeta = __builtin_amdgcn_exp2f(-0.33333333333333333f * l); // v_exp_f32
        float s    = copysignf(zeta * zeta, det);
        float hz = 0.5f * zeta;
        float hs = 0.5f * s;

        float n00 = hz*U[0][0] + c00*hs;
        float n01 = hz*U[0][1] + c10*hs;
        float n02 = hz*U[0][2] + c20*hs;
        float n10 = hz*U[1][0] + c01*hs;
        float n11 = hz*U[1][1] + c11*hs;
        float n12 = hz*U[1][2] + c21*hs;
        float n20 = hz*U[2][0] + c02*hs;
        float n21 = hz*U[2][1] + c12*hs;
        float n22 = hz*U[2][2] + c22*hs;
        U[0][0]=n00; U[0][1]=n01; U[0][2]=n02;
        U[1][0]=n10; U[1][1]=n11; U[1][2]=n12;
        U[2][0]=n20; U[2][1]=n21; U[2][2]=n22;
    }

    // ---- trilinear warp of 6 channels ----
    float cx = (float)h + u[0];
    float cy = (float)w + u[1];
    float cz = (float)d + u[2];
    float flx = floorf(cx), fly = floorf(cy), flz = floorf(cz);
    float fx = cx - flx, fy = cy - fly, fz = cz - flz;
    int x0 = (int)flx, y0 = (int)fly, z0 = (int)flz;
    int xi[2], yi[2], zi[2];
    xi[0] = min(max(x0,     0), NH - 1); xi[1] = min(max(x0 + 1, 0), NH - 1);
    yi[0] = min(max(y0,     0), NW - 1); yi[1] = min(max(y0 + 1, 0), NW - 1);
    zi[0] = min(max(z0,     0), ND - 1); zi[1] = min(max(z0 + 1, 0), ND - 1);
    float wx[2] = {1.0f - fx, fx};
    float wy[2] = {1.0f - fy, fy};
    float wz[2] = {1.0f - fz, fz};

    const float* img = dti + b * 6 * HWD;
    float acc[6] = {0.f, 0.f, 0.f, 0.f, 0.f, 0.f};
#pragma unroll
    for (int i = 0; i < 2; ++i) {
#pragma unroll
        for (int j = 0; j < 2; ++j) {
            int rowoff = (xi[i] * NW + yi[j]) * ND;
            float wij = wx[i] * wy[j];
#pragma unroll
            for (int k = 0; k < 2; ++k) {
                float wgt = wij * wz[k];
                int lin = rowoff + zi[k];
#pragma unroll
                for (int ch = 0; ch < 6; ++ch)
                    acc[ch] += wgt * img[ch * HWD + lin];
            }
        }
    }

    // ---- T = R^T D R, output lower-tri ----
    float Dm[3][3];
    Dm[0][0] = acc[0]; Dm[0][1] = acc[1]; Dm[0][2] = acc[3];
    Dm[1][0] = acc[1]; Dm[1][1] = acc[2]; Dm[1][2] = acc[4];
    Dm[2][0] = acc[3]; Dm[2][1] = acc[4]; Dm[2][2] = acc[5];

    float M[3][3];
#pragma unroll
    for (int i = 0; i < 3; ++i)
#pragma unroll
        for (int k = 0; k < 3; ++k)
            M[i][k] = U[0][i]*Dm[0][k] + U[1][i]*Dm[1][k] + U[2][i]*Dm[2][k];

    float T00 = M[0][0]*U[0][0] + M[0][1]*U[1][0] + M[0][2]*U[2][0];
    float T10 = M[1][0]*U[0][0] + M[1][1]*U[1][0] + M[1][2]*U[2][0];
    float T11 = M[1][0]*U[0][1] + M[1][1]*U[1][1] + M[1][2]*U[2][1];
    float T20 = M[2][0]*U[0][0] + M[2][1]*U[1][0] + M[2][2]*U[2][0];
    float T21 = M[2][0]*U[0][1] + M[2][1]*U[1][1] + M[2][2]*U[2][1];
    float T22 = M[2][0]*U[0][2] + M[2][1]*U[1][2] + M[2][2]*U[2][2];

    float* obase = out + b * 6 * HWD + sp;
    obase[0]       = T00;
    obase[HWD]     = T10;
    obase[2 * HWD] = T11;
    obase[3 * HWD] = T20;
    obase[4 * HWD] = T21;
    obase[5 * HWD] = T22;
}

extern "C" void kernel_launch(void* const* d_in, const int* in_sizes, int n_in,
                              void* d_out, int out_size, void* d_ws, size_t ws_size,
                              hipStream_t stream) {
    const float* dti = (const float*)d_in[0];
    const float* ddf = (const float*)d_in[1];
    float* o = (float*)d_out;
    const int n = NB * HWD;   // 4,194,304 voxels
    warp_dti_kernel<<<n / 256, 256, 0, stream>>>(dti, ddf, o);
}